// Round 6
// baseline (838.311 us; speedup 1.0000x reference)
//
#include <hip/hip_runtime.h>
#include <math.h>

#define NN 100000
#define NE 1600000
#define DD 64
#define ED 16
#define BROWS 192                    // rows per bin (LDS accum 192*64*4 = 48 KB)
#define NBIN 521                     // ceil(NN/BROWS)
#define NBIN_PAD 544
#define BCAP 3840                    // slots per bin (mean 3072, +14 sigma)
#define EPB 4096                     // edges per binA block
#define NBLKA ((NE + EPB - 1) / EPB) // 391

// ws layout (4-byte words):
//   xpb    [NN*DD] bf16   word 0          (3,200,000 words, 12.8 MB)
//   cursor [544]   int    word 3,200,000
//   binned [544*3840] int2 word 3,200,544 (byte 12,802,176 — 8B aligned; 16.7 MB)
// total ~29.5 MB

__device__ __forceinline__ unsigned short f2bf(float f) {
    unsigned int b = __float_as_uint(f);
    unsigned int r = (b + 0x7FFFu + ((b >> 16) & 1u)) >> 16;   // RNE
    return (unsigned short)r;
}
__device__ __forceinline__ float bf2f(unsigned short u) {
    return __uint_as_float(((unsigned int)u) << 16);
}

// K1: xpb[n][o] = bf16(x[n]·W_node[o] + b_node[o]); block 0 also inits cursors.
__global__ __launch_bounds__(256) void proj_kernel(
    const float* __restrict__ x, const float* __restrict__ Wn,
    const float* __restrict__ bn, unsigned short* __restrict__ xpb,
    int* __restrict__ cursor) {
    __shared__ float4 xs[64 * 16];   // 16 KB
    int tid = threadIdx.x;
    if (blockIdx.x == 0) {           // cursor init (next kernel waits on stream)
        cursor[tid] = tid * BCAP;
        cursor[tid + 256] = (tid + 256) * BCAP;
        if (tid < NBIN_PAD - 512) cursor[tid + 512] = (tid + 512) * BCAP;
    }
    int o = tid & 63;
    int wave = tid >> 6;
    float4 Wr[16];
    const float4* Wn4 = reinterpret_cast<const float4*>(Wn);
#pragma unroll
    for (int k = 0; k < 16; ++k) Wr[k] = Wn4[o * 16 + k];
    float bo = bn[o];
    int n0 = blockIdx.x * 64;
    const float4* x4 = reinterpret_cast<const float4*>(x);
    long base = (long)n0 * 16;
    long limit = (long)NN * 16;
#pragma unroll
    for (int i = 0; i < 4; ++i) {
        long idx = base + tid + 256 * i;
        xs[tid + 256 * i] = (idx < limit) ? x4[idx] : make_float4(0.f, 0.f, 0.f, 0.f);
    }
    __syncthreads();
#pragma unroll
    for (int j = 0; j < 16; ++j) {
        int ln = wave * 16 + j;
        int n = n0 + ln;
        if (n >= NN) break;          // wave-uniform
        float acc = bo;
#pragma unroll
        for (int k = 0; k < 16; ++k) {
            float4 a = xs[ln * 16 + k];   // wave-uniform LDS addr -> broadcast
            acc += a.x * Wr[k].x + a.y * Wr[k].y + a.z * Wr[k].z + a.w * Wr[k].w;
        }
        xpb[(long)n * DD + o] = f2bf(acc);
    }
}

// K2 (binA): LDS multisplit of edges into 521 row-bins. Per block: histogram ->
// one cursor atomicAdd per touched bin -> chunk-contiguous packed writes.
// Entry: w0 = (rowlocal<<17)|col, w1 = gate f32 bits.
__global__ __launch_bounds__(256) void binA_kernel(
    const int* __restrict__ ei, const float* __restrict__ ef,
    const float* __restrict__ We, const float* __restrict__ be,
    int* __restrict__ cursor, int2* __restrict__ binned) {
    __shared__ int cnt[NBIN_PAD];
    __shared__ int base[NBIN_PAD];
    int tid = threadIdx.x;
    int e0 = blockIdx.x * EPB;
    cnt[tid] = 0; cnt[tid + 256] = 0;
    if (tid < NBIN_PAD - 512) cnt[tid + 512] = 0;
    __syncthreads();
    int rows[16], cols[16];
#pragma unroll
    for (int i = 0; i < 16; ++i) {
        int e = e0 + tid + 256 * i;          // coalesced
        bool ok = e < NE;
        rows[i] = ok ? ei[e] : -1;
        cols[i] = ok ? ei[NE + e] : 0;
        if (ok) atomicAdd(&cnt[rows[i] / BROWS], 1);
    }
    __syncthreads();
    {
        int c = cnt[tid];
        base[tid] = c ? atomicAdd(&cursor[tid], c) : 0;
        c = cnt[tid + 256];
        base[tid + 256] = c ? atomicAdd(&cursor[tid + 256], c) : 0;
        if (tid < NBIN_PAD - 512) {
            c = cnt[tid + 512];
            base[tid + 512] = c ? atomicAdd(&cursor[tid + 512], c) : 0;
        }
    }
    __syncthreads();
    cnt[tid] = 0; cnt[tid + 256] = 0;        // reuse as local claim counters
    if (tid < NBIN_PAD - 512) cnt[tid + 512] = 0;
    __syncthreads();
    const float4* We4 = reinterpret_cast<const float4*>(We);
    float4 w0 = We4[0], w1 = We4[1], w2 = We4[2], w3 = We4[3];
    float bb = be[0];
#pragma unroll
    for (int i = 0; i < 16; ++i) {
        int e = e0 + tid + 256 * i;
        if (e < NE) {
            const float4* ef4 = reinterpret_cast<const float4*>(ef + (size_t)e * ED);
            float4 a0 = ef4[0], a1 = ef4[1], a2 = ef4[2], a3 = ef4[3];
            float d = a0.x * w0.x + a0.y * w0.y + a0.z * w0.z + a0.w * w0.w
                    + a1.x * w1.x + a1.y * w1.y + a1.z * w1.z + a1.w * w1.w
                    + a2.x * w2.x + a2.y * w2.y + a2.z * w2.z + a2.w * w2.w
                    + a3.x * w3.x + a3.y * w3.y + a3.z * w3.z + a3.w * w3.w + bb;
            float g = 1.f / (1.f + expf(-d));
            int r = rows[i], c = cols[i];
            int bin = r / BROWS;
            int rl = r - bin * BROWS;
            int pos = base[bin] + atomicAdd(&cnt[bin], 1);
            binned[pos] = make_int2((rl << 17) | c, __float_as_int(g));
        }
    }
}

// K3 (binB): one block per bin. LDS f32 accumulator [192][64] + LDS deg.
// 8 waves x 8-wide ILP over the bin's edges; lane = channel; gather bf16 xpb,
// LDS atomicAdd (lane->bank 2-way, free). Coalesced out write, /max(deg,1).
__global__ __launch_bounds__(512) void binB_kernel(
    const unsigned short* __restrict__ xpb, const int* __restrict__ cursor,
    const int2* __restrict__ binned, float* __restrict__ out) {
    __shared__ float acc[BROWS * DD];   // 48 KB
    __shared__ int degL[BROWS];
    int tid = threadIdx.x;
    int lane = tid & 63;
    int wv = tid >> 6;
    int b = blockIdx.x;
    float4* acc4 = reinterpret_cast<float4*>(acc);
#pragma unroll
    for (int i = 0; i < 6; ++i) acc4[tid + 512 * i] = make_float4(0.f, 0.f, 0.f, 0.f);
    if (tid < BROWS) degL[tid] = 0;
    __syncthreads();
    int bstart = b * BCAP;
    int nb = cursor[b] - bstart;        // edges in this bin
    for (int t = wv * 8; t < nb; t += 64) {
        const int4* p = reinterpret_cast<const int4*>(binned + (size_t)bstart + t);
        int4 q0 = p[0], q1 = p[1], q2 = p[2], q3 = p[3];   // 8 packed entries
#define ENT(W0, W1, K) { \
        bool ok = (t + (K)) < nb; \
        int w = ok ? (W0) : 0; \
        float g = ok ? __int_as_float(W1) : 0.f; \
        int col = w & 0x1FFFF; \
        int rl = (w >> 17) & 0xFF; \
        float v = bf2f(xpb[(size_t)col * DD + lane]); \
        atomicAdd(&acc[rl * DD + lane], g * v); \
        if (ok && lane == 0) atomicAdd(&degL[rl], 1); }
        ENT(q0.x, q0.y, 0) ENT(q0.z, q0.w, 1)
        ENT(q1.x, q1.y, 2) ENT(q1.z, q1.w, 3)
        ENT(q2.x, q2.y, 4) ENT(q2.z, q2.w, 5)
        ENT(q3.x, q3.y, 6) ENT(q3.z, q3.w, 7)
#undef ENT
    }
    __syncthreads();
    int row0 = b * BROWS;
#pragma unroll
    for (int i = 0; i < 6; ++i) {
        int lin = tid + 512 * i;        // 0..3071 float4 units (192 rows x 16)
        int rl = lin >> 4;
        int row = row0 + rl;
        if (row < NN) {
            float dv = fmaxf((float)degL[rl], 1.f);
            float4 a = acc4[lin];
            float4 o = make_float4(a.x / dv, a.y / dv, a.z / dv, a.w / dv);
            reinterpret_cast<float4*>(out)[(size_t)row * 16 + (lin & 15)] = o;
        }
    }
}

extern "C" void kernel_launch(void* const* d_in, const int* in_sizes, int n_in,
                              void* d_out, int out_size, void* d_ws, size_t ws_size,
                              hipStream_t stream) {
    const float* x  = (const float*)d_in[0];
    const int*   ei = (const int*)d_in[1];   // [2, NE] int32
    const float* ef = (const float*)d_in[2];
    const float* We = (const float*)d_in[3];
    const float* be = (const float*)d_in[4];
    const float* Wn = (const float*)d_in[5];
    const float* bn = (const float*)d_in[6];
    float* out = (float*)d_out;

    unsigned short* xpb = (unsigned short*)d_ws;
    int*  cursor = (int*)d_ws + 3200000;
    int2* binned = (int2*)((int*)d_ws + 3200544);

    proj_kernel<<<(NN + 63) / 64, 256, 0, stream>>>(x, Wn, bn, xpb, cursor);
    binA_kernel<<<NBLKA, 256, 0, stream>>>(ei, ef, We, be, cursor, binned);
    binB_kernel<<<NBIN, 512, 0, stream>>>(xpb, cursor, binned, out);
}

// Round 7
// 249.205 us; speedup vs baseline: 3.3639x; 3.3639x over previous
//
#include <hip/hip_runtime.h>
#include <math.h>

#define NN 100000
#define NE 1600000
#define DD 64
#define ED 16
#define SCAN_B 1024
#define NB1 ((NN + SCAN_B - 1) / SCAN_B)   // 98
#define EPC 16384                          // edges per fill chunk
#define NCH ((NE + EPC - 1) / EPC)         // 98
#define RPR 12500                          // rows per XCD range (NN/8)

// ws layout (4-byte words):
//   xpb   [NN*DD]  bf16(ushort)  word 0          (3,200,000 words)
//   deg   [NN]     int           word 3,200,000
//   cur   [NN]     int           word 3,300,000
//   bsum  [1024]   int           word 3,400,000
//   bbase [1024]   int           word 3,401,024
//   csr   [<=3.2M] int2          word 3,402,048  (byte 13,608,192 — 128B aligned)
// total ≈ 39.2 MB

__device__ __forceinline__ unsigned short f2bf(float f) {
    unsigned int b = __float_as_uint(f);
    unsigned int r = (b + 0x7FFFu + ((b >> 16) & 1u)) >> 16;   // RNE
    return (unsigned short)r;
}

// K1: xpb[n][o] = bf16(x[n]·W_node[o] + b_node[o]); also zeroes deg.
__global__ __launch_bounds__(256) void proj_kernel(
    const float* __restrict__ x, const float* __restrict__ Wn,
    const float* __restrict__ bn, unsigned short* __restrict__ xpb,
    int* __restrict__ deg) {
    __shared__ float4 xs[64 * 16];   // 16 KB
    int tid = threadIdx.x;
    int gi = blockIdx.x * 256 + tid;
    if (gi < NN) deg[gi] = 0;        // grid covers NN (1563*256 = 400128)
    int o = tid & 63;
    int wave = tid >> 6;
    float4 Wr[16];
    const float4* Wn4 = reinterpret_cast<const float4*>(Wn);
#pragma unroll
    for (int k = 0; k < 16; ++k) Wr[k] = Wn4[o * 16 + k];
    float bo = bn[o];
    int n0 = blockIdx.x * 64;
    const float4* x4 = reinterpret_cast<const float4*>(x);
    long base = (long)n0 * 16;
    long limit = (long)NN * 16;
#pragma unroll
    for (int i = 0; i < 4; ++i) {
        long idx = base + tid + 256 * i;
        xs[tid + 256 * i] = (idx < limit) ? x4[idx] : make_float4(0.f, 0.f, 0.f, 0.f);
    }
    __syncthreads();
#pragma unroll
    for (int j = 0; j < 16; ++j) {
        int ln = wave * 16 + j;
        int n = n0 + ln;
        if (n >= NN) break;          // wave-uniform
        float acc = bo;
#pragma unroll
        for (int k = 0; k < 16; ++k) {
            float4 a = xs[ln * 16 + k];   // wave-uniform LDS addr -> broadcast
            acc += a.x * Wr[k].x + a.y * Wr[k].y + a.z * Wr[k].z + a.w * Wr[k].w;
        }
        xpb[(long)n * DD + o] = f2bf(acc);
    }
}

// K2: degree histogram, 4 edges/thread via int4
__global__ __launch_bounds__(256) void count_kernel(const int4* __restrict__ ei4,
                                                    int* __restrict__ deg) {
    int i = blockIdx.x * 256 + threadIdx.x;
    if (i < NE / 4) {
        int4 r = ei4[i];
        atomicAdd(&deg[r.x], 1);
        atomicAdd(&deg[r.y], 1);
        atomicAdd(&deg[r.z], 1);
        atomicAdd(&deg[r.w], 1);
    }
}

// S1: per-block scan of PADDED degrees (round-up-16) -> local exclusive
// offsets in cur, block total in bsum.
__global__ __launch_bounds__(SCAN_B) void scan1_kernel(const int* __restrict__ deg,
                                                       int* __restrict__ cur,
                                                       int* __restrict__ bsum) {
    __shared__ int s[SCAN_B];
    int t = threadIdx.x;
    int i = blockIdx.x * SCAN_B + t;
    int v = (i < NN) ? ((deg[i] + 15) & ~15) : 0;
    s[t] = v;
    __syncthreads();
    for (int off = 1; off < SCAN_B; off <<= 1) {
        int add = (t >= off) ? s[t - off] : 0;
        __syncthreads();
        s[t] += add;
        __syncthreads();
    }
    if (i < NN) cur[i] = s[t] - v;
    if (t == SCAN_B - 1) bsum[blockIdx.x] = s[t];
}

// S2: exclusive scan of block totals (single block)
__global__ void scan2_kernel(const int* __restrict__ bsum, int* __restrict__ bbase) {
    __shared__ int s[NB1];
    int t = threadIdx.x;
    if (t < NB1) s[t] = bsum[t];
    __syncthreads();
    if (t == 0) {
        int run = 0;
        for (int b = 0; b < NB1; ++b) { int x = s[b]; s[b] = run; run += x; }
    }
    __syncthreads();
    if (t < NB1) bbase[t] = s[t];
}

// K3b: zero-fill the pad slots [start+deg, start+pdeg) of every row.
// Runs BEFORE fill (cur still holds local exclusive starts).
__global__ __launch_bounds__(256) void pad_kernel(
    const int* __restrict__ deg, const int* __restrict__ cur,
    const int* __restrict__ bbase, int2* __restrict__ csr) {
    int n = blockIdx.x * 256 + threadIdx.x;
    if (n >= NN) return;
    int d = deg[n];
    int pd = (d + 15) & ~15;
    int start = cur[n] + bbase[n >> 10];
    for (int j = start + d; j < start + pd; ++j) csr[j] = make_int2(0, 0);
}

// K4: range-partitioned fill. Block b: range k=b&7 (rows [k*RPR,(k+1)*RPR)),
// edge chunk c=b>>3. Only edges whose row is in-range are processed here, so
// csr slots + cur counters of a range are written by one XCD's blocks
// (blockIdx%8 round-robin heuristic) -> no cross-XCD partial-line writeback.
__global__ __launch_bounds__(256) void fill_kernel(
    const int* __restrict__ ei, const float* __restrict__ ef,
    const float* __restrict__ We, const float* __restrict__ be,
    int* __restrict__ cur, const int* __restrict__ bbase,
    int2* __restrict__ csr) {
    int k = blockIdx.x & 7;
    int c = blockIdx.x >> 3;
    int rlo = k * RPR, rhi = rlo + RPR;
    int e0 = c * EPC;
    const float4* We4 = reinterpret_cast<const float4*>(We);
    float4 w0 = We4[0], w1 = We4[1], w2 = We4[2], w3 = We4[3];
    float bb = be[0];
    const int4* rows4 = reinterpret_cast<const int4*>(ei + e0);
#pragma unroll 4
    for (int it = 0; it < 16; ++it) {
        int idx4 = threadIdx.x + it * 256;       // int4 index within chunk
        int ebase = e0 + idx4 * 4;
        if (ebase >= NE) break;                  // NE%4==0 -> full int4 valid
        int4 r = rows4[idx4];
#define DOEDGE(RR, OFF) { \
        int row = (RR); \
        if (row >= rlo && row < rhi) { \
            int e = ebase + (OFF); \
            int col = ei[NE + e]; \
            const float4* ef4 = reinterpret_cast<const float4*>(ef + (size_t)e * ED); \
            float4 a0 = ef4[0], a1 = ef4[1], a2 = ef4[2], a3 = ef4[3]; \
            float d = a0.x*w0.x + a0.y*w0.y + a0.z*w0.z + a0.w*w0.w \
                    + a1.x*w1.x + a1.y*w1.y + a1.z*w1.z + a1.w*w1.w \
                    + a2.x*w2.x + a2.y*w2.y + a2.z*w2.z + a2.w*w2.w \
                    + a3.x*w3.x + a3.y*w3.y + a3.z*w3.z + a3.w*w3.w + bb; \
            float g = 1.f / (1.f + expf(-d)); \
            int pos = atomicAdd(&cur[row], 1) + bbase[row >> 10]; \
            csr[pos] = make_int2(col, __float_as_int(g)); \
        } }
        DOEDGE(r.x, 0) DOEDGE(r.y, 1) DOEDGE(r.z, 2) DOEDGE(r.w, 3)
#undef DOEDGE
    }
}

// K5: one wave per node, lane-halves paired over entries. Each int4 csr load
// covers 2 entries; lanes 0-31 gather entry A (ushort2 = channels 2l,2l+1),
// lanes 32-63 entry B -> 2 lines per gather instruction, 16 entries per trip
// in 8 gathers. shfl_xor(32) combine, float2 coalesced store.
__global__ __launch_bounds__(256) void gather_kernel(
    const unsigned short* __restrict__ xpb, const int* __restrict__ deg,
    const int* __restrict__ cur, const int* __restrict__ bbase,
    const int2* __restrict__ csr, float* __restrict__ out) {
    int tid = threadIdx.x;
    int lane = tid & 63;
    int half = lane >> 5;
    int hl = lane & 31;
    int n = blockIdx.x * 4 + (tid >> 6);
    if (n >= NN) return;
    int dn = deg[n];
    int start = cur[n] + bbase[n >> 10] - dn;   // after fill: cur = local_start + deg
    int pdn = (dn + 15) & ~15;
    float ax = 0.f, ay = 0.f;
    for (int j = start; j < start + pdn; j += 16) {
        const int4* c4 = reinterpret_cast<const int4*>(csr + j);  // 128B aligned
        int4 e0 = c4[0], e1 = c4[1], e2 = c4[2], e3 = c4[3];
        int4 e4 = c4[4], e5 = c4[5], e6 = c4[6], e7 = c4[7];
#define PAIR(E) { \
        int col = half ? (E).z : (E).x; \
        float g = __int_as_float(half ? (E).w : (E).y); \
        unsigned int u = *reinterpret_cast<const unsigned int*>(xpb + (size_t)col * DD + 2 * hl); \
        float lo = __uint_as_float((u & 0xFFFFu) << 16); \
        float hi = __uint_as_float(u & 0xFFFF0000u); \
        ax += g * lo; ay += g * hi; }
        PAIR(e0) PAIR(e1) PAIR(e2) PAIR(e3)
        PAIR(e4) PAIR(e5) PAIR(e6) PAIR(e7)
#undef PAIR
    }
    // channel-pair c: full sum = lo-half lane c + hi-half lane c+32
    ax += __shfl_xor(ax, 32);
    ay += __shfl_xor(ay, 32);
    if (half == 0) {
        float dv = fmaxf((float)dn, 1.f);
        reinterpret_cast<float2*>(out)[(size_t)n * 32 + hl] =
            make_float2(ax / dv, ay / dv);
    }
}

extern "C" void kernel_launch(void* const* d_in, const int* in_sizes, int n_in,
                              void* d_out, int out_size, void* d_ws, size_t ws_size,
                              hipStream_t stream) {
    const float* x  = (const float*)d_in[0];
    const int*   ei = (const int*)d_in[1];   // [2, NE] int32
    const float* ef = (const float*)d_in[2];
    const float* We = (const float*)d_in[3];
    const float* be = (const float*)d_in[4];
    const float* Wn = (const float*)d_in[5];
    const float* bn = (const float*)d_in[6];
    float* out = (float*)d_out;

    unsigned short* xpb = (unsigned short*)d_ws;
    int*  deg   = (int*)d_ws + 3200000;
    int*  cur   = (int*)d_ws + 3300000;
    int*  bsum  = (int*)d_ws + 3400000;
    int*  bbase = (int*)d_ws + 3401024;
    int2* csr   = (int2*)((int*)d_ws + 3402048);

    proj_kernel<<<(NN + 63) / 64, 256, 0, stream>>>(x, Wn, bn, xpb, deg);
    count_kernel<<<(NE / 4 + 255) / 256, 256, 0, stream>>>((const int4*)ei, deg);
    scan1_kernel<<<NB1, SCAN_B, 0, stream>>>(deg, cur, bsum);
    scan2_kernel<<<1, 128, 0, stream>>>(bsum, bbase);
    pad_kernel<<<(NN + 255) / 256, 256, 0, stream>>>(deg, cur, bbase, csr);
    fill_kernel<<<NCH * 8, 256, 0, stream>>>(ei, ef, We, be, cur, bbase, csr);
    gather_kernel<<<(NN + 3) / 4, 256, 0, stream>>>(xpb, deg, cur, bbase, csr, out);
}